// Round 16
// baseline (314.143 us; speedup 1.0000x reference)
//
#include <hip/hip_runtime.h>
#include <hip/hip_bf16.h>

// SACRSN_v84 — v16: wave-specialized row kernel (3 barriers instead of 8).
// Each wave owns an independent dependency chain end-to-end:
//   w0: sens clinear -> vis palette;   w1: wgate/addr/top3/eff -> aud palette
//   w2: q,k clinears -> gate -> sim/attn/read;   w3: v,quad clinears
// nm (tanh+LN) partitioned across waves post-barrier, fully wave-local.
// vq_kernel / finalize verbatim from R11/R12 (verified).

#define NROWS 8
#define NBLOCKS 1024
#define RSTRIDE 4736

static constexpr size_t OFF_VQLOSS = 38797312UL;
static constexpr size_t OFF_IDX    = 38805504UL;
static constexpr size_t OFF_SENT   = 38813696UL;
static constexpr size_t OFF_NENT   = 38813697UL;

struct Params {
  const float* curr_r; const float* curr_i;
  const float* mem_r;  const float* mem_i;
  const float* codebook;
  const float* qkv_Wr; const float* qkv_Wi; const float* qkv_br; const float* qkv_bi;
  const float* quad_Wr; const float* quad_Wi; const float* quad_br; const float* quad_bi;
  const float* sens_Wr; const float* sens_Wi; const float* sens_br; const float* sens_bi;
  const float* vis_pal; const float* aud_pal;
  const float* gate_W; const float* gate_b;
  const float* addr_W; const float* addr_b;
  const float* ln_gr; const float* ln_br; const float* ln_gi; const float* ln_bi;
  float* out;
  int* hist;
  float* rowent;
};

__global__ __launch_bounds__(256) void row_wave(Params P) {
  const int b = blockIdx.x;
  const int t = threadIdx.x;
  const int lane = t & 63;
  const int wv = t >> 6;

  __shared__ float zr[64], zi[64];
  __shared__ float sfl[128];
  __shared__ float s_eff[32];
  __shared__ float s_vr[64], s_vi[64];
  __shared__ float s_vo[128], s_ao[128];
  __shared__ float s_pvp[32], s_pap[32];
  __shared__ float s_attn[32];
  __shared__ float s_gate_s;

  const size_t bb = (size_t)b;
  const size_t mbase = bb * 2048;
  float* orow = P.out + bb * RSTRIDE;

  // ---- stage z ----
  if (t < 64)       zr[t]      = P.curr_r[bb * 64 + t];
  else if (t < 128) zi[t - 64] = P.curr_i[bb * 64 + (t - 64)];
  __syncthreads();   // B1

  // ================= Phase 1 =================
  if (wv == 0) {
    // sens clinear (lane = j), verbatim R6 body
    const int j = lane;
    float aRR = 0.f, aRI = 0.f, aIR = 0.f, aII = 0.f;
    for (int d = 0; d < 64; ++d) {
      const float xr = zr[d], xi = zi[d];
      const float wr = P.sens_Wr[d * 64 + j], wi = P.sens_Wi[d * 64 + j];
      aRR += xr * wr; aRI += xr * wi; aIR += xi * wr; aII += xi * wi;
    }
    sfl[j]      = (aRR + P.sens_br[j]) - (aII + P.sens_bi[j]);
    sfl[64 + j] = (aRI + P.sens_bi[j]) + (aIR + P.sens_br[j]);
  } else if (wv == 1) {
    // wgate (full-wave butterfly) then addr softmax/entropy/top3/eff (lanes<32)
    float tw = zr[lane] * P.gate_W[lane] + zi[lane] * P.gate_W[64 + lane];
    #pragma unroll
    for (int m = 1; m <= 32; m <<= 1) tw += __shfl_xor(tw, m);
    const float wgate = 1.f / (1.f + expf(-(tw + P.gate_b[0])));
    if (lane < 32) {
      const int l = lane;
      float lg = P.addr_b[l];
      for (int d = 0; d < 64; ++d) lg += zr[d] * P.addr_W[d * 32 + l];
      for (int d = 0; d < 64; ++d) lg += zi[d] * P.addr_W[(64 + d) * 32 + l];
      float mx = lg;
      #pragma unroll
      for (int m = 16; m >= 1; m >>= 1) mx = fmaxf(mx, __shfl_xor(mx, m));
      float e = expf(lg - mx);
      float sm = e;
      #pragma unroll
      for (int m = 16; m >= 1; m >>= 1) sm += __shfl_xor(sm, m);
      const float w = e / sm;
      float es = -(w * logf(w + 1e-10f));
      #pragma unroll
      for (int m = 16; m >= 1; m >>= 1) es += __shfl_xor(es, m);
      if (l == 0) P.rowent[b] = es;
      // top-3 (lax.top_k: ties -> lower index)
      const float myw = w;
      bool picked = false;
      float val = w; int idx = l;
      float sumtop = 0.f;
      #pragma unroll
      for (int it = 0; it < 3; ++it) {
        float v2 = val; int i2 = idx;
        #pragma unroll
        for (int m = 16; m >= 1; m >>= 1) {
          float ov = __shfl_xor(v2, m); int oi = __shfl_xor(i2, m);
          if (ov > v2 || (ov == v2 && oi < i2)) { v2 = ov; i2 = oi; }
        }
        sumtop += v2;
        if (l == i2) { picked = true; val = -1e30f; }
      }
      s_eff[l] = picked ? wgate * (myw / (sumtop + 1e-6f)) : 0.f;
    }
  } else if (wv == 2) {
    // q then k (regs only), then gate
    const int j = lane;
    float qR, qI, kR, kI;
    {
      float aRR = 0.f, aRI = 0.f, aIR = 0.f, aII = 0.f;
      for (int d = 0; d < 64; ++d) {
        const float xr = zr[d], xi = zi[d];
        const float wr = P.qkv_Wr[d * 64 + j], wi = P.qkv_Wi[d * 64 + j];
        aRR += xr * wr; aRI += xr * wi; aIR += xi * wr; aII += xi * wi;
      }
      qR = (aRR + P.qkv_br[j]) - (aII + P.qkv_bi[j]);
      qI = (aRI + P.qkv_bi[j]) + (aIR + P.qkv_br[j]);
    }
    {
      float aRR = 0.f, aRI = 0.f, aIR = 0.f, aII = 0.f;
      for (int d = 0; d < 64; ++d) {
        const float xr = zr[d], xi = zi[d];
        const float wr = P.qkv_Wr[4096 + d * 64 + j], wi = P.qkv_Wi[4096 + d * 64 + j];
        aRR += xr * wr; aRI += xr * wi; aIR += xi * wr; aII += xi * wi;
      }
      kR = (aRR + P.qkv_br[64 + j]) - (aII + P.qkv_bi[64 + j]);
      kI = (aRI + P.qkv_bi[64 + j]) + (aIR + P.qkv_br[64 + j]);
    }
    float g = qR * kR + qI * kI;
    #pragma unroll
    for (int m = 1; m <= 32; m <<= 1) g += __shfl_xor(g, m);
    if (lane == 0) s_gate_s = 1.f / (1.f + expf(-g));
  } else {
    // v then quad
    const int j = lane;
    {
      float aRR = 0.f, aRI = 0.f, aIR = 0.f, aII = 0.f;
      for (int d = 0; d < 64; ++d) {
        const float xr = zr[d], xi = zi[d];
        const float wr = P.qkv_Wr[8192 + d * 64 + j], wi = P.qkv_Wi[8192 + d * 64 + j];
        aRR += xr * wr; aRI += xr * wi; aIR += xi * wr; aII += xi * wi;
      }
      s_vr[j] = (aRR + P.qkv_br[128 + j]) - (aII + P.qkv_bi[128 + j]);
      s_vi[j] = (aRI + P.qkv_bi[128 + j]) + (aIR + P.qkv_br[128 + j]);
    }
    {
      float aRR = 0.f, aRI = 0.f, aIR = 0.f, aII = 0.f;
      for (int d = 0; d < 64; ++d) {
        const float xr = zr[d], xi = zi[d];
        const float wr = P.quad_Wr[d * 64 + j], wi = P.quad_Wi[d * 64 + j];
        aRR += xr * wr; aRI += xr * wi; aIR += xi * wr; aII += xi * wi;
      }
      const float oR = (aRR + P.quad_br[j]) - (aII + P.quad_bi[j]);
      const float oI = (aRI + P.quad_bi[j]) + (aIR + P.quad_br[j]);
      orow[512 + j] = -oI;   // q_r = -zi
      orow[576 + j] = oR;    // q_i =  zr
    }
  }
  __syncthreads();   // B2  (sfl, s_eff, s_gate_s, s_vr/s_vi ready)

  // ---- LN params per lane (hot, reused by nm) ----
  const float gR_ = P.ln_gr[lane], bR_ = P.ln_br[lane];
  const float gI_ = P.ln_gi[lane], bI_ = P.ln_bi[lane];

  // nm helper: slot fully within-wave (lane = d)
  auto do_nm = [&](int s2) {
    const float a = P.mem_r[mbase + s2 * 64 + lane];
    const float c = P.mem_i[mbase + s2 * 64 + lane];
    const float e = s_eff[s2];
    const float nr = tanhf(a + e * (zr[lane] - a));
    const float ni = tanhf(c + e * (zi[lane] - c));
    float sR = nr, sI = ni;
    #pragma unroll
    for (int m = 1; m <= 32; m <<= 1) { sR += __shfl_xor(sR, m); sI += __shfl_xor(sI, m); }
    const float mR = sR * (1.f / 64.f), mI = sI * (1.f / 64.f);
    const float dr = nr - mR, di = ni - mI;
    float vR = dr * dr, vI = di * di;
    #pragma unroll
    for (int m = 1; m <= 32; m <<= 1) { vR += __shfl_xor(vR, m); vI += __shfl_xor(vI, m); }
    const float invR = 1.f / sqrtf(vR * (1.f / 64.f) + 1e-6f);
    const float invI = 1.f / sqrtf(vI * (1.f / 64.f) + 1e-6f);
    orow[640  + s2 * 64 + lane] = dr * invR * gR_ + bR_;
    orow[2688 + s2 * 64 + lane] = di * invI * gI_ + bI_;
  };

  // ================= Phase 2 =================
  if (wv == 0) {
    // vis palette: scores (lanes<32), softmax, attend-out
    if (lane < 32) {
      float sc = 0.f;
      const float* p = P.vis_pal + (size_t)lane * 128;
      for (int x = 0; x < 128; ++x) sc += sfl[x] * p[x];
      float mx = sc;
      #pragma unroll
      for (int m = 16; m >= 1; m >>= 1) mx = fmaxf(mx, __shfl_xor(mx, m));
      float e = expf(sc - mx);
      float sm = e;
      #pragma unroll
      for (int m = 16; m >= 1; m >>= 1) sm += __shfl_xor(sm, m);
      s_pvp[lane] = e / sm;
    }
    float v0 = 0.f, v1 = 0.f;
    for (int a = 0; a < 32; ++a) {
      const float pw = s_pvp[a];
      v0 += pw * P.vis_pal[a * 128 + lane];
      v1 += pw * P.vis_pal[a * 128 + 64 + lane];
    }
    s_vo[lane] = v0; s_vo[64 + lane] = v1;
    #pragma unroll
    for (int s2 = 24; s2 < 28; ++s2) do_nm(s2);
  } else if (wv == 1) {
    // aud palette
    if (lane < 32) {
      float sc = 0.f;
      const float* p = P.aud_pal + (size_t)lane * 128;
      for (int x = 0; x < 128; ++x) sc += sfl[x] * p[x];
      float mx = sc;
      #pragma unroll
      for (int m = 16; m >= 1; m >>= 1) mx = fmaxf(mx, __shfl_xor(mx, m));
      float e = expf(sc - mx);
      float sm = e;
      #pragma unroll
      for (int m = 16; m >= 1; m >>= 1) sm += __shfl_xor(sm, m);
      s_pap[lane] = e / sm;
    }
    float v0 = 0.f, v1 = 0.f;
    for (int a = 0; a < 32; ++a) {
      const float pw = s_pap[a];
      v0 += pw * P.aud_pal[a * 128 + lane];
      v1 += pw * P.aud_pal[a * 128 + 64 + lane];
    }
    s_ao[lane] = v0; s_ao[64 + lane] = v1;
    #pragma unroll
    for (int s2 = 28; s2 < 32; ++s2) do_nm(s2);
  } else if (wv == 2) {
    // sim / attn / read  (lane l: slot s=l>>1, d-half = (l&1)*32)
    const int s2 = lane >> 1, dh = (lane & 1) * 32;
    float sp = 0.f;
    {
      const float* mrp = P.mem_r + mbase + s2 * 64 + dh;
      const float* mip = P.mem_i + mbase + s2 * 64 + dh;
      #pragma unroll
      for (int c4 = 0; c4 < 32; c4 += 4) {
        const float4 m4 = *(const float4*)&mrp[c4];
        const float4 n4 = *(const float4*)&mip[c4];
        sp += m4.x * zr[dh + c4]     + m4.y * zr[dh + c4 + 1]
            + m4.z * zr[dh + c4 + 2] + m4.w * zr[dh + c4 + 3]
            + n4.x * zi[dh + c4]     + n4.y * zi[dh + c4 + 1]
            + n4.z * zi[dh + c4 + 2] + n4.w * zi[dh + c4 + 3];
      }
    }
    sp += __shfl_xor(sp, 1);               // full sim for slot s2 (both lanes)
    float mx = sp;
    #pragma unroll
    for (int m = 1; m <= 32; m <<= 1) mx = fmaxf(mx, __shfl_xor(mx, m));
    float e = expf(sp - mx);
    float sm = e;
    #pragma unroll
    for (int m = 1; m <= 32; m <<= 1) sm += __shfl_xor(sm, m);
    const float aw = e / (sm * 0.5f);      // values duplicated x2 across lanes
    if ((lane & 1) == 0) s_attn[s2] = aw;
    // read: lane = d, re-stream mem (L2-hot)
    float rr = 0.f, ri = 0.f;
    for (int s3 = 0; s3 < 32; ++s3) {
      const float at = s_attn[s3];
      rr += at * P.mem_r[mbase + s3 * 64 + lane];
      ri += at * P.mem_i[mbase + s3 * 64 + lane];
    }
    orow[256 + lane] = rr;
    orow[320 + lane] = ri;
    #pragma unroll
    for (int s3 = 16; s3 < 24; ++s3) do_nm(s3);
  } else {
    #pragma unroll
    for (int s2 = 0; s2 < 16; ++s2) do_nm(s2);
  }
  __syncthreads();   // B3  (s_vo, s_ao ready)

  // ================= tails =================
  if (wv == 0)      orow[128 + lane] = s_vr[lane] * s_gate_s;              // g_r
  else if (wv == 1) orow[192 + lane] = s_vi[lane] * s_gate_s;              // g_i
  else if (wv == 2) orow[384 + lane] = s_vo[lane] - s_ao[64 + lane];       // exp_r
  else              orow[448 + lane] = s_vo[64 + lane] + s_ao[lane];       // exp_i
}

// ================= vq_kernel: unchanged (verified R11/R12) =================
__global__ __launch_bounds__(256) void vq_kernel(Params P) {
  const int t = threadIdx.x;
  const int bid = blockIdx.x;
  const int lane = t & 63;
  const int wv = t >> 6;

  __shared__ __align__(16) float s_zr[NROWS][64], s_zi[NROWS][64];
  __shared__ double s_cbn[128];
  __shared__ double s_dall[NROWS][256];
  __shared__ float s_vqls[NROWS];
  __shared__ int s_idx[NROWS];

  {
    const float* cr = P.curr_r + (size_t)bid * (NROWS * 64);
    const float* ci = P.curr_i + (size_t)bid * (NROWS * 64);
    float* zr = &s_zr[0][0];
    float* zi = &s_zi[0][0];
    for (int i = t; i < NROWS * 64; i += 256) { zr[i] = cr[i]; zi[i] = ci[i]; }
  }
  {
    const float* cb = P.codebook + (t & 127) * 128 + (t >> 7) * 64;
    double a = 0.0;
    for (int d = 0; d < 64; ++d) { double w = (double)cb[d]; a = fma(w, w, a); }
    s_dall[0][t] = a;
    __syncthreads();
    if (t < 128) s_cbn[t] = s_dall[0][t] + s_dall[0][t + 128];
    __syncthreads();
  }
  {
    const int c = t & 127, h = t >> 7;
    const float* cb = P.codebook + c * 128 + h * 64;
    const float (*zb)[64] = h ? s_zi : s_zr;
    double acc[NROWS];
    #pragma unroll
    for (int r = 0; r < NROWS; ++r) acc[r] = 0.0;
    for (int d = 0; d < 64; ++d) {
      const double w = (double)cb[d];
      #pragma unroll
      for (int r = 0; r < NROWS; ++r) acc[r] = fma(w, (double)zb[r][d], acc[r]);
    }
    #pragma unroll
    for (int r = 0; r < NROWS; ++r) s_dall[r][h * 128 + c] = acc[r];
    __syncthreads();
    #pragma unroll
    for (int rr = 0; rr < 2; ++rr) {
      const int r = wv * 2 + rr;
      const double d0 = s_cbn[lane]      - 2.0 * (s_dall[r][lane]      + s_dall[r][128 + lane]);
      const double d1 = s_cbn[lane + 64] - 2.0 * (s_dall[r][64 + lane] + s_dall[r][192 + lane]);
      double sv = d0; int si = lane;
      if (d1 < sv) { sv = d1; si = lane + 64; }
      #pragma unroll
      for (int m = 1; m <= 32; m <<= 1) {
        double ov = __shfl_xor(sv, m);
        int oi = __shfl_xor(si, m);
        if (ov < sv || (ov == sv && oi < si)) { sv = ov; si = oi; }
      }
      if (lane == 0) { s_idx[r] = si; atomicAdd(&P.hist[si], 1); }
    }
    __syncthreads();
  }
  {
    #pragma unroll
    for (int rr = 0; rr < 2; ++rr) {
      const int r = wv * 2 + rr;
      const float* cb = P.codebook + (size_t)s_idx[r] * 128;
      float d0_ = cb[lane] - s_zr[r][lane];
      float d1_ = cb[64 + lane] - s_zi[r][lane];
      float v = d0_ * d0_ + d1_ * d1_;
      #pragma unroll
      for (int m = 1; m <= 32; m <<= 1) v += __shfl_xor(v, m);
      if (lane == 0) s_vqls[r] = 0.25f * v * (1.0f / 128.0f);
    }
  }
  __syncthreads();
  {
    const int j = t & 63, g = t >> 6;
    #pragma unroll
    for (int rr = 0; rr < 4; ++rr) {
      const int r = (g >> 1) * 4 + rr;
      float* orow = P.out + ((size_t)bid * NROWS + r) * RSTRIDE;
      const float* cb = P.codebook + (size_t)s_idx[r] * 128;
      if ((g & 1) == 0) {
        float z = s_zr[r][j];
        orow[j] = z + (cb[j] - z);
      } else {
        float z = s_zi[r][j];
        orow[64 + j] = z + (cb[64 + j] - z);
      }
    }
  }
  if (t < NROWS) {
    P.out[OFF_VQLOSS + (size_t)bid * NROWS + t] = s_vqls[t];
    P.out[OFF_IDX + (size_t)bid * NROWS + t] = (float)s_idx[t];
  }
}

__global__ __launch_bounds__(256) void finalize_k(const int* hist, const float* rowent,
                                                  float* out) {
  const int t = threadIdx.x;
  __shared__ float red[256];
  float se = 0.f;
  for (int i = t; i < 8192; i += 256) se += rowent[i];
  red[t] = se;
  __syncthreads();
  for (int off = 128; off >= 1; off >>= 1) {
    if (t < off) red[t] += red[t + off];
    __syncthreads();
  }
  if (t == 0) out[OFF_SENT] = red[0] / 8192.0f;
  __syncthreads();
  float ne = 0.f;
  if (t < 128) {
    const float pp = (float)hist[t] / 8192.0f;
    ne = -(pp * logf(pp + 1e-10f));
  }
  red[t] = ne;
  __syncthreads();
  for (int off = 128; off >= 1; off >>= 1) {
    if (t < off) red[t] += red[t + off];
    __syncthreads();
  }
  if (t == 0) out[OFF_NENT] = red[0] / logf(128.0f);
}

extern "C" void kernel_launch(void* const* d_in, const int* in_sizes, int n_in,
                              void* d_out, int out_size, void* d_ws, size_t ws_size,
                              hipStream_t stream) {
  (void)in_sizes; (void)n_in; (void)out_size; (void)ws_size;
  Params P;
  P.curr_r   = (const float*)d_in[0];
  P.curr_i   = (const float*)d_in[1];
  P.mem_r    = (const float*)d_in[2];
  P.mem_i    = (const float*)d_in[3];
  P.codebook = (const float*)d_in[4];
  P.qkv_Wr   = (const float*)d_in[5];
  P.qkv_Wi   = (const float*)d_in[6];
  P.qkv_br   = (const float*)d_in[7];
  P.qkv_bi   = (const float*)d_in[8];
  P.quad_Wr  = (const float*)d_in[9];
  P.quad_Wi  = (const float*)d_in[10];
  P.quad_br  = (const float*)d_in[11];
  P.quad_bi  = (const float*)d_in[12];
  P.sens_Wr  = (const float*)d_in[13];
  P.sens_Wi  = (const float*)d_in[14];
  P.sens_br  = (const float*)d_in[15];
  P.sens_bi  = (const float*)d_in[16];
  P.vis_pal  = (const float*)d_in[17];
  P.aud_pal  = (const float*)d_in[18];
  P.gate_W   = (const float*)d_in[19];
  P.gate_b   = (const float*)d_in[20];
  P.addr_W   = (const float*)d_in[21];
  P.addr_b   = (const float*)d_in[22];
  P.ln_gr    = (const float*)d_in[23];
  P.ln_br    = (const float*)d_in[24];
  P.ln_gi    = (const float*)d_in[25];
  P.ln_bi    = (const float*)d_in[26];
  P.out = (float*)d_out;
  P.hist = (int*)d_ws;
  P.rowent = (float*)((char*)d_ws + 512);

  hipMemsetAsync(d_ws, 0, 512, stream);
  row_wave<<<dim3(8192), dim3(256), 0, stream>>>(P);
  vq_kernel<<<dim3(NBLOCKS), dim3(256), 0, stream>>>(P);
  finalize_k<<<dim3(1), dim3(256), 0, stream>>>(P.hist, P.rowent, (float*)d_out);
}

// Round 17
// 239.886 us; speedup vs baseline: 1.3096x; 1.3096x over previous
//
#include <hip/hip_runtime.h>
#include <hip/hip_bf16.h>

// SACRSN_v84 — v17: merge vq (1024 blocks) + row work (8192 blocks) into ONE
// launch (branch on blockIdx) to remove serialized-launch overhead.
// All math bodies verbatim from verified R12 (row path) and R11 (vq path).

#define NROWS 8
#define RSTRIDE 4736

static constexpr size_t OFF_VQLOSS = 38797312UL;
static constexpr size_t OFF_IDX    = 38805504UL;
static constexpr size_t OFF_SENT   = 38813696UL;
static constexpr size_t OFF_NENT   = 38813697UL;

struct Params {
  const float* curr_r; const float* curr_i;
  const float* mem_r;  const float* mem_i;
  const float* codebook;
  const float* qkv_Wr; const float* qkv_Wi; const float* qkv_br; const float* qkv_bi;
  const float* quad_Wr; const float* quad_Wi; const float* quad_br; const float* quad_bi;
  const float* sens_Wr; const float* sens_Wi; const float* sens_br; const float* sens_bi;
  const float* vis_pal; const float* aud_pal;
  const float* gate_W; const float* gate_b;
  const float* addr_W; const float* addr_b;
  const float* ln_gr; const float* ln_br; const float* ln_gi; const float* ln_bi;
  float* out;
  int* hist;
  float* rowent;
};

union __align__(16) SharedU {
  struct {          // row path
    float zr[64], zi[64];
    float s_qr[64], s_qi[64], s_kr[64], s_ki[64], s_vr[64], s_vi[64];
    float sfl[128];
    float s_sp[4][4][64];
    float lp[4][32];
    float s_eff[32];
    float s_sim[32], s_attn[32];
    float s_rr[4][8][8], s_ri[4][8][8];
    float s_pv[4][32], s_pa[4][32];
    float s_pvp[32], s_pap[32];
    float s_vo[128], s_ao[128];
    float s_wg, s_gate;
  } r;
  struct {          // vq path
    float s_zr[NROWS][64], s_zi[NROWS][64];
    double s_cbn[128];
    double s_dall[NROWS][256];
    float s_vqls[NROWS];
    int s_idx[NROWS];
  } v;
};

__global__ __launch_bounds__(256) void main_kernel(Params P) {
  __shared__ SharedU u;
  const int t = threadIdx.x;
  const int lane = t & 63;
  const int wv = t >> 6;

  if (blockIdx.x < 1024) {
    // ================= VQ path (verbatim R11 vq_kernel, bid = blockIdx) ======
    const int bid = blockIdx.x;
    {
      const float* cr = P.curr_r + (size_t)bid * (NROWS * 64);
      const float* ci = P.curr_i + (size_t)bid * (NROWS * 64);
      float* zr = &u.v.s_zr[0][0];
      float* zi = &u.v.s_zi[0][0];
      for (int i = t; i < NROWS * 64; i += 256) { zr[i] = cr[i]; zi[i] = ci[i]; }
    }
    {
      const float* cb = P.codebook + (t & 127) * 128 + (t >> 7) * 64;
      double a = 0.0;
      for (int d = 0; d < 64; ++d) { double w = (double)cb[d]; a = fma(w, w, a); }
      u.v.s_dall[0][t] = a;
      __syncthreads();
      if (t < 128) u.v.s_cbn[t] = u.v.s_dall[0][t] + u.v.s_dall[0][t + 128];
      __syncthreads();
    }
    {
      const int c = t & 127, h = t >> 7;
      const float* cb = P.codebook + c * 128 + h * 64;
      const float (*zb)[64] = h ? u.v.s_zi : u.v.s_zr;
      double acc[NROWS];
      #pragma unroll
      for (int r = 0; r < NROWS; ++r) acc[r] = 0.0;
      for (int d = 0; d < 64; ++d) {
        const double w = (double)cb[d];
        #pragma unroll
        for (int r = 0; r < NROWS; ++r) acc[r] = fma(w, (double)zb[r][d], acc[r]);
      }
      #pragma unroll
      for (int r = 0; r < NROWS; ++r) u.v.s_dall[r][h * 128 + c] = acc[r];
      __syncthreads();
      #pragma unroll
      for (int rr = 0; rr < 2; ++rr) {
        const int r = wv * 2 + rr;
        const double d0 = u.v.s_cbn[lane]      - 2.0 * (u.v.s_dall[r][lane]      + u.v.s_dall[r][128 + lane]);
        const double d1 = u.v.s_cbn[lane + 64] - 2.0 * (u.v.s_dall[r][64 + lane] + u.v.s_dall[r][192 + lane]);
        double sv = d0; int si = lane;
        if (d1 < sv) { sv = d1; si = lane + 64; }
        #pragma unroll
        for (int m = 1; m <= 32; m <<= 1) {
          double ov = __shfl_xor(sv, m);
          int oi = __shfl_xor(si, m);
          if (ov < sv || (ov == sv && oi < si)) { sv = ov; si = oi; }
        }
        if (lane == 0) { u.v.s_idx[r] = si; atomicAdd(&P.hist[si], 1); }
      }
      __syncthreads();
    }
    {
      #pragma unroll
      for (int rr = 0; rr < 2; ++rr) {
        const int r = wv * 2 + rr;
        const float* cb = P.codebook + (size_t)u.v.s_idx[r] * 128;
        float d0_ = cb[lane] - u.v.s_zr[r][lane];
        float d1_ = cb[64 + lane] - u.v.s_zi[r][lane];
        float v = d0_ * d0_ + d1_ * d1_;
        #pragma unroll
        for (int m = 1; m <= 32; m <<= 1) v += __shfl_xor(v, m);
        if (lane == 0) u.v.s_vqls[r] = 0.25f * v * (1.0f / 128.0f);
      }
    }
    __syncthreads();
    {
      const int j = t & 63, g = t >> 6;
      #pragma unroll
      for (int rr = 0; rr < 4; ++rr) {
        const int r = (g >> 1) * 4 + rr;
        float* orow = P.out + ((size_t)bid * NROWS + r) * RSTRIDE;
        const float* cb = P.codebook + (size_t)u.v.s_idx[r] * 128;
        if ((g & 1) == 0) {
          float z = u.v.s_zr[r][j];
          orow[j] = z + (cb[j] - z);
        } else {
          float z = u.v.s_zi[r][j];
          orow[64 + j] = z + (cb[64 + j] - z);
        }
      }
    }
    if (t < NROWS) {
      P.out[OFF_VQLOSS + (size_t)bid * NROWS + t] = u.v.s_vqls[t];
      P.out[OFF_IDX + (size_t)bid * NROWS + t] = (float)u.v.s_idx[t];
    }
    return;
  }

  // ================= Row path (verbatim R12 row_main, b = blockIdx-1024) ====
  const int b = blockIdx.x - 1024;
  const size_t bb = (size_t)b;
  const int s = t >> 3, k = t & 7, d0 = k * 8;
  const float* mrp = P.mem_r + ((bb * 32 + s) * 64 + d0);
  const float* mip = P.mem_i + ((bb * 32 + s) * 64 + d0);
  float4 a0 = *(const float4*)mrp, a1 = *(const float4*)(mrp + 4);
  float4 b0 = *(const float4*)mip, b1 = *(const float4*)(mip + 4);
  float mr[8] = {a0.x, a0.y, a0.z, a0.w, a1.x, a1.y, a1.z, a1.w};
  float mi[8] = {b0.x, b0.y, b0.z, b0.w, b1.x, b1.y, b1.z, b1.w};

  if (t < 64)       u.r.zr[t]      = P.curr_r[bb * 64 + t];
  else if (t < 128) u.r.zi[t - 64] = P.curr_i[bb * 64 + (t - 64)];
  __syncthreads();

  float* orow = P.out + bb * RSTRIDE;

  // ---- B: clinears q,k,v,quad (wave=cl) + sens partials ----
  {
    const int j = lane, cl = wv;
    const float *Wr, *Wi, *br_, *bi_;
    if      (cl == 0) { Wr = P.qkv_Wr;        Wi = P.qkv_Wi;        br_ = P.qkv_br;       bi_ = P.qkv_bi;       }
    else if (cl == 1) { Wr = P.qkv_Wr + 4096; Wi = P.qkv_Wi + 4096; br_ = P.qkv_br + 64;  bi_ = P.qkv_bi + 64;  }
    else if (cl == 2) { Wr = P.qkv_Wr + 8192; Wi = P.qkv_Wi + 8192; br_ = P.qkv_br + 128; bi_ = P.qkv_bi + 128; }
    else              { Wr = P.quad_Wr;       Wi = P.quad_Wi;       br_ = P.quad_br;      bi_ = P.quad_bi;      }
    float aRR = 0.f, aRI = 0.f, aIR = 0.f, aII = 0.f;
    for (int d = 0; d < 64; ++d) {
      const float xr = u.r.zr[d], xi = u.r.zi[d];
      const float wr = Wr[d * 64 + j], wi = Wi[d * 64 + j];
      aRR += xr * wr; aRI += xr * wi; aIR += xi * wr; aII += xi * wi;
    }
    const float oR = (aRR + br_[j]) - (aII + bi_[j]);
    const float oI = (aRI + bi_[j]) + (aIR + br_[j]);
    if      (cl == 0) { u.r.s_qr[j] = oR; u.r.s_qi[j] = oI; }
    else if (cl == 1) { u.r.s_kr[j] = oR; u.r.s_ki[j] = oI; }
    else if (cl == 2) { u.r.s_vr[j] = oR; u.r.s_vi[j] = oI; }
    else              { orow[512 + j] = -oI; orow[576 + j] = oR; }
    float bRR = 0.f, bRI = 0.f, bIR = 0.f, bII = 0.f;
    for (int dd = 0; dd < 16; ++dd) {
      const int d = wv * 16 + dd;
      const float xr = u.r.zr[d], xi = u.r.zi[d];
      const float wr = P.sens_Wr[d * 64 + j], wi = P.sens_Wi[d * 64 + j];
      bRR += xr * wr; bRI += xr * wi; bIR += xi * wr; bII += xi * wi;
    }
    u.r.s_sp[wv][0][j] = bRR; u.r.s_sp[wv][1][j] = bRI;
    u.r.s_sp[wv][2][j] = bIR; u.r.s_sp[wv][3][j] = bII;
  }
  __syncthreads();

  // ---- C: sim partials + addr partials + wgate + gate ----
  {
    float sp = 0.f;
    #pragma unroll
    for (int x = 0; x < 8; ++x) sp += mr[x] * u.r.zr[d0 + x] + mi[x] * u.r.zi[d0 + x];
    sp += __shfl_xor(sp, 1); sp += __shfl_xor(sp, 2); sp += __shfl_xor(sp, 4);
    if (k == 0) u.r.s_sim[s] = sp;
  }
  if (t < 128) {
    const int q = t >> 5, l = t & 31;
    const float* zz = (q < 2) ? u.r.zr : u.r.zi;
    const int zb = (q & 1) * 32;
    float a = 0.f;
    for (int i = 0; i < 32; ++i) a += zz[zb + i] * P.addr_W[(q * 32 + i) * 32 + l];
    u.r.lp[q][l] = a;
  } else if (t < 192) {
    const int j = t - 128;
    float tw = u.r.zr[j] * P.gate_W[j] + u.r.zi[j] * P.gate_W[64 + j];
    #pragma unroll
    for (int m = 1; m <= 32; m <<= 1) tw += __shfl_xor(tw, m);
    if (j == 0) u.r.s_wg = tw;
  } else {
    const int j = t - 192;
    float g = u.r.s_qr[j] * u.r.s_kr[j] + u.r.s_qi[j] * u.r.s_ki[j];
    #pragma unroll
    for (int m = 1; m <= 32; m <<= 1) g += __shfl_xor(g, m);
    if (j == 0) u.r.s_gate = 1.f / (1.f + expf(-g));
  }
  __syncthreads();

  // ---- D: sim softmax | addr softmax/top3/eff | sens combine ----
  if (t < 32) {
    float v = u.r.s_sim[t];
    float mx = v;
    #pragma unroll
    for (int m = 16; m >= 1; m >>= 1) mx = fmaxf(mx, __shfl_xor(mx, m));
    float e = expf(v - mx);
    float sm = e;
    #pragma unroll
    for (int m = 16; m >= 1; m >>= 1) sm += __shfl_xor(sm, m);
    u.r.s_attn[t] = e / sm;
  } else if (t >= 64 && t < 96) {
    const int l = t - 64;
    float lg = u.r.lp[0][l] + u.r.lp[1][l] + u.r.lp[2][l] + u.r.lp[3][l] + P.addr_b[l];
    float mx = lg;
    #pragma unroll
    for (int m = 16; m >= 1; m >>= 1) mx = fmaxf(mx, __shfl_xor(mx, m));
    float e = expf(lg - mx);
    float sm = e;
    #pragma unroll
    for (int m = 16; m >= 1; m >>= 1) sm += __shfl_xor(sm, m);
    const float w = e / sm;
    float es = -(w * logf(w + 1e-10f));
    #pragma unroll
    for (int m = 16; m >= 1; m >>= 1) es += __shfl_xor(es, m);
    if (l == 0) P.rowent[b] = es;
    const float myw = w;
    bool picked = false;
    float val = w; int idx = l;
    float sumtop = 0.f;
    #pragma unroll
    for (int it = 0; it < 3; ++it) {
      float v2 = val; int i2 = idx;
      #pragma unroll
      for (int m = 16; m >= 1; m >>= 1) {
        float ov = __shfl_xor(v2, m); int oi = __shfl_xor(i2, m);
        if (ov > v2 || (ov == v2 && oi < i2)) { v2 = ov; i2 = oi; }
      }
      sumtop += v2;
      if (l == i2) { picked = true; val = -1e30f; }
    }
    const float wgate = 1.f / (1.f + expf(-(u.r.s_wg + P.gate_b[0])));
    u.r.s_eff[l] = picked ? wgate * (myw / (sumtop + 1e-6f)) : 0.f;
  } else if (t >= 128 && t < 192) {
    const int j = t - 128;
    const float aRR = u.r.s_sp[0][0][j] + u.r.s_sp[1][0][j] + u.r.s_sp[2][0][j] + u.r.s_sp[3][0][j];
    const float aRI = u.r.s_sp[0][1][j] + u.r.s_sp[1][1][j] + u.r.s_sp[2][1][j] + u.r.s_sp[3][1][j];
    const float aIR = u.r.s_sp[0][2][j] + u.r.s_sp[1][2][j] + u.r.s_sp[2][2][j] + u.r.s_sp[3][2][j];
    const float aII = u.r.s_sp[0][3][j] + u.r.s_sp[1][3][j] + u.r.s_sp[2][3][j] + u.r.s_sp[3][3][j];
    const float oR = (aRR + P.sens_br[j]) - (aII + P.sens_bi[j]);
    const float oI = (aRI + P.sens_bi[j]) + (aIR + P.sens_br[j]);
    u.r.sfl[j] = oR; u.r.sfl[64 + j] = oI;
  }
  __syncthreads();

  // ---- E: read partials + tanh/LN + palette partials ----
  const float aw = u.r.s_attn[s];
  {
    float pr[8], pi[8];
    #pragma unroll
    for (int x = 0; x < 8; ++x) { pr[x] = aw * mr[x]; pi[x] = aw * mi[x]; }
    #pragma unroll
    for (int m = 8; m <= 32; m <<= 1) {
      #pragma unroll
      for (int x = 0; x < 8; ++x) { pr[x] += __shfl_xor(pr[x], m); pi[x] += __shfl_xor(pi[x], m); }
    }
    if (lane < 8) {
      #pragma unroll
      for (int x = 0; x < 8; ++x) { u.r.s_rr[wv][lane][x] = pr[x]; u.r.s_ri[wv][lane][x] = pi[x]; }
    }
  }
  {
    const float eff = u.r.s_eff[s];
    float nr[8], ni[8];
    #pragma unroll
    for (int x = 0; x < 8; ++x) {
      nr[x] = tanhf(mr[x] + eff * (u.r.zr[d0 + x] - mr[x]));
      ni[x] = tanhf(mi[x] + eff * (u.r.zi[d0 + x] - mi[x]));
    }
    float sR = 0.f, sI = 0.f;
    #pragma unroll
    for (int x = 0; x < 8; ++x) { sR += nr[x]; sI += ni[x]; }
    sR += __shfl_xor(sR, 1); sR += __shfl_xor(sR, 2); sR += __shfl_xor(sR, 4);
    sI += __shfl_xor(sI, 1); sI += __shfl_xor(sI, 2); sI += __shfl_xor(sI, 4);
    const float mR = sR * (1.f / 64.f), mI = sI * (1.f / 64.f);
    float vR = 0.f, vI = 0.f;
    #pragma unroll
    for (int x = 0; x < 8; ++x) {
      const float dr = nr[x] - mR; vR += dr * dr;
      const float di = ni[x] - mI; vI += di * di;
    }
    vR += __shfl_xor(vR, 1); vR += __shfl_xor(vR, 2); vR += __shfl_xor(vR, 4);
    vI += __shfl_xor(vI, 1); vI += __shfl_xor(vI, 2); vI += __shfl_xor(vI, 4);
    const float invR = 1.f / sqrtf(vR * (1.f / 64.f) + 1e-6f);
    const float invI = 1.f / sqrtf(vI * (1.f / 64.f) + 1e-6f);
    float oR[8], oI[8];
    #pragma unroll
    for (int x = 0; x < 8; ++x) {
      const int d = d0 + x;
      oR[x] = (nr[x] - mR) * invR * P.ln_gr[d] + P.ln_br[d];
      oI[x] = (ni[x] - mI) * invI * P.ln_gi[d] + P.ln_bi[d];
    }
    *(float4*)&orow[640 + s * 64 + d0]      = make_float4(oR[0], oR[1], oR[2], oR[3]);
    *(float4*)&orow[640 + s * 64 + d0 + 4]  = make_float4(oR[4], oR[5], oR[6], oR[7]);
    *(float4*)&orow[2688 + s * 64 + d0]     = make_float4(oI[0], oI[1], oI[2], oI[3]);
    *(float4*)&orow[2688 + s * 64 + d0 + 4] = make_float4(oI[4], oI[5], oI[6], oI[7]);
  }
  if (t < 128) {
    const int a = t & 31, q = t >> 5;
    float sc = 0.f;
    for (int x = q * 32; x < q * 32 + 32; ++x) sc += u.r.sfl[x] * P.vis_pal[a * 128 + x];
    u.r.s_pv[q][a] = sc;
  } else {
    const int tt = t - 128, a = tt & 31, q = tt >> 5;
    float sc = 0.f;
    for (int x = q * 32; x < q * 32 + 32; ++x) sc += u.r.sfl[x] * P.aud_pal[a * 128 + x];
    u.r.s_pa[q][a] = sc;
  }
  __syncthreads();

  // ---- F: read combine | vis softmax | aud softmax ----
  if (t < 64) {
    const int kk = t >> 3, xx = t & 7;
    const float rv = u.r.s_rr[0][kk][xx] + u.r.s_rr[1][kk][xx] + u.r.s_rr[2][kk][xx] + u.r.s_rr[3][kk][xx];
    const float iv = u.r.s_ri[0][kk][xx] + u.r.s_ri[1][kk][xx] + u.r.s_ri[2][kk][xx] + u.r.s_ri[3][kk][xx];
    orow[256 + t] = rv;
    orow[320 + t] = iv;
  } else if (t >= 128 && t < 160) {
    const int a = t - 128;
    float sc = u.r.s_pv[0][a] + u.r.s_pv[1][a] + u.r.s_pv[2][a] + u.r.s_pv[3][a];
    float mx = sc;
    #pragma unroll
    for (int m = 16; m >= 1; m >>= 1) mx = fmaxf(mx, __shfl_xor(mx, m));
    float e = expf(sc - mx);
    float sm = e;
    #pragma unroll
    for (int m = 16; m >= 1; m >>= 1) sm += __shfl_xor(sm, m);
    u.r.s_pvp[a] = e / sm;
  } else if (t >= 192 && t < 224) {
    const int a = t - 192;
    float sc = u.r.s_pa[0][a] + u.r.s_pa[1][a] + u.r.s_pa[2][a] + u.r.s_pa[3][a];
    float mx = sc;
    #pragma unroll
    for (int m = 16; m >= 1; m >>= 1) mx = fmaxf(mx, __shfl_xor(mx, m));
    float e = expf(sc - mx);
    float sm = e;
    #pragma unroll
    for (int m = 16; m >= 1; m >>= 1) sm += __shfl_xor(sm, m);
    u.r.s_pap[a] = e / sm;
  }
  __syncthreads();

  // ---- G: palette attend-out + g writes ----
  if (t < 128) {
    float v = 0.f;
    for (int a = 0; a < 32; ++a) v += u.r.s_pvp[a] * P.vis_pal[a * 128 + t];
    u.r.s_vo[t] = v;
  } else {
    const int j = t - 128;
    float v = 0.f;
    for (int a = 0; a < 32; ++a) v += u.r.s_pap[a] * P.aud_pal[a * 128 + j];
    u.r.s_ao[j] = v;
  }
  if (t < 64)       orow[128 + t] = u.r.s_vr[t] * u.r.s_gate;
  else if (t < 128) orow[192 + (t - 64)] = u.r.s_vi[t - 64] * u.r.s_gate;
  __syncthreads();

  // ---- H: exp_r / exp_i ----
  if (t < 64)       orow[384 + t] = u.r.s_vo[t] - u.r.s_ao[64 + t];
  else if (t < 128) orow[448 + (t - 64)] = u.r.s_vo[t] + u.r.s_ao[t - 64];
}

__global__ __launch_bounds__(256) void finalize_k(const int* hist, const float* rowent,
                                                  float* out) {
  const int t = threadIdx.x;
  __shared__ float red[256];
  float se = 0.f;
  for (int i = t; i < 8192; i += 256) se += rowent[i];
  red[t] = se;
  __syncthreads();
  for (int off = 128; off >= 1; off >>= 1) {
    if (t < off) red[t] += red[t + off];
    __syncthreads();
  }
  if (t == 0) out[OFF_SENT] = red[0] / 8192.0f;
  __syncthreads();
  float ne = 0.f;
  if (t < 128) {
    const float pp = (float)hist[t] / 8192.0f;
    ne = -(pp * logf(pp + 1e-10f));
  }
  red[t] = ne;
  __syncthreads();
  for (int off = 128; off >= 1; off >>= 1) {
    if (t < off) red[t] += red[t + off];
    __syncthreads();
  }
  if (t == 0) out[OFF_NENT] = red[0] / logf(128.0f);
}

extern "C" void kernel_launch(void* const* d_in, const int* in_sizes, int n_in,
                              void* d_out, int out_size, void* d_ws, size_t ws_size,
                              hipStream_t stream) {
  (void)in_sizes; (void)n_in; (void)out_size; (void)ws_size;
  Params P;
  P.curr_r   = (const float*)d_in[0];
  P.curr_i   = (const float*)d_in[1];
  P.mem_r    = (const float*)d_in[2];
  P.mem_i    = (const float*)d_in[3];
  P.codebook = (const float*)d_in[4];
  P.qkv_Wr   = (const float*)d_in[5];
  P.qkv_Wi   = (const float*)d_in[6];
  P.qkv_br   = (const float*)d_in[7];
  P.qkv_bi   = (const float*)d_in[8];
  P.quad_Wr  = (const float*)d_in[9];
  P.quad_Wi  = (const float*)d_in[10];
  P.quad_br  = (const float*)d_in[11];
  P.quad_bi  = (const float*)d_in[12];
  P.sens_Wr  = (const float*)d_in[13];
  P.sens_Wi  = (const float*)d_in[14];
  P.sens_br  = (const float*)d_in[15];
  P.sens_bi  = (const float*)d_in[16];
  P.vis_pal  = (const float*)d_in[17];
  P.aud_pal  = (const float*)d_in[18];
  P.gate_W   = (const float*)d_in[19];
  P.gate_b   = (const float*)d_in[20];
  P.addr_W   = (const float*)d_in[21];
  P.addr_b   = (const float*)d_in[22];
  P.ln_gr    = (const float*)d_in[23];
  P.ln_br    = (const float*)d_in[24];
  P.ln_gi    = (const float*)d_in[25];
  P.ln_bi    = (const float*)d_in[26];
  P.out = (float*)d_out;
  P.hist = (int*)d_ws;
  P.rowent = (float*)((char*)d_ws + 512);

  hipMemsetAsync(d_ws, 0, 512, stream);
  main_kernel<<<dim3(1024 + 8192), dim3(256), 0, stream>>>(P);
  finalize_k<<<dim3(1), dim3(256), 0, stream>>>(P.hist, P.rowent, (float*)d_out);
}